// Round 7
// baseline (285.446 us; speedup 1.0000x reference)
//
#include <hip/hip_runtime.h>

// ---------------------------------------------------------------------------
// SparseAttention on MI355X (gfx950)
// hidden=2048, heads=16, d=128, topk=256, N=2048, B=1
//
// Ranking path (fp32/fp64, exact):  imp[h,m] = hs[m,:] . U[:,h]
// K/V computed gather-first (256 selected rows per head).
// gemm_qkv: 128x64 tiles, 640 blocks, PAIRED K-steps — one vmcnt(6)+s_barrier
//   per TWO BK=32 steps (16 MFMA/barrier), 6 LDS buffers (72 KB, 2 blocks/CU).
//   Plain addressing (no LDS swizzle / XCD remap — both were net-negative here;
//   conflicts are hidden under the barrier-bound critical path).
// gemm_o / attn: round-6 state (XOR chunk swizzle + XCD remap, conflicts=0).
// ---------------------------------------------------------------------------

typedef __attribute__((ext_vector_type(8))) short bf16x8;
typedef __attribute__((ext_vector_type(8))) unsigned short u16x8;
typedef __attribute__((ext_vector_type(4))) float f32x4;

__device__ __forceinline__ unsigned short f2bf(float x) {
    unsigned u = __float_as_uint(x);
    u += 0x7fffu + ((u >> 16) & 1u);      // round to nearest even
    return (unsigned short)(u >> 16);
}

__device__ __forceinline__ void load_lds16(const unsigned short* g, unsigned short* l) {
    __builtin_amdgcn_global_load_lds(
        (const __attribute__((address_space(1))) unsigned int*)g,
        (__attribute__((address_space(3))) unsigned int*)l,
        16, 0, 0);
}

struct Ptr4  { const float* p[4]; };

// ---------------------------------------------------------------------------
// Combined QKV GEMM, tile 128x64, BK=32, 256 threads (2x2 waves), 640 blocks.
// bid <  128: gathered K/V block (h, j-tile, d-tile decode).
// bid >= 128: Q block, 4x8 supertiled. Writes Qb (+bq), bf16.
// PAIRED pipeline: 6 LDS buffers; per barrier: retire pair p (vmcnt(6)),
// stage pair p+2 into bufs freed by pair p-1, compute pair p (16 MFMA).
// ---------------------------------------------------------------------------
__global__ __launch_bounds__(256) void gemm_qkv(
    const unsigned short* __restrict__ HSb,   // [2048][2048] bf16
    const unsigned short* __restrict__ WT4,   // WqT|WkT|WvT|WoT, each [n][k] bf16
    const float* __restrict__ bq,
    const float* __restrict__ bk,
    const float* __restrict__ bv,
    const int* __restrict__ idx,              // [16][256] forward map
    unsigned short* __restrict__ Qb,          // [2048][2048]
    unsigned short* __restrict__ Ksel,        // [16][256][128]
    unsigned short* __restrict__ VselT)       // [16][128][256]
{
    __shared__ __align__(16) unsigned short As[6][128][32];   // 48 KB
    __shared__ __align__(16) unsigned short Bs[6][64][32];    // 24 KB

    const int tid  = threadIdx.x;
    const int lane = tid & 63;
    const int wave = tid >> 6;
    const int wm = wave >> 1, wn = wave & 1;
    const int lr = lane >> 2;          // 0..15 row within 16-row staging group
    const int lc = (lane & 3) * 8;     // bf16 col offset (16B chunk)

    const int bid = blockIdx.x;

    int kv, h = 0, bm, bn;
    const unsigned short* Bt;
    long ar0, ar1;                     // global A rows for this lane's two stages
    if (bid < 128) {
        kv = 1 + (bid >> 6);                        // 1=K, 2=V
        const int t = bid & 63;
        h  = t >> 2;
        bm = ((t >> 1) & 1) * 128;                  // j-tile base within head
        bn = h * 128 + (t & 1) * 64;                // d-tile base in WT row space
        Bt = WT4 + (long)kv * 4194304;
        ar0 = idx[h * 256 + bm + wave * 16 + lr];
        ar1 = idx[h * 256 + bm + wave * 16 + 64 + lr];
    } else {
        kv = 0;
        const int t = bid - 128;
        const int st = t >> 5, u = t & 31;          // supertile: 4 M-tiles x 8 N-tiles
        bm = ((st >> 2) * 4 + (u >> 3)) * 128;
        bn = ((st & 3) * 8 + (u & 7)) * 64;
        Bt = WT4;                                   // WqT
        ar0 = bm + wave * 16 + lr;
        ar1 = ar0 + 64;
    }

    const unsigned short* Arow0 = HSb + ar0 * 2048 + lc;
    const unsigned short* Arow1 = HSb + ar1 * 2048 + lc;
    const unsigned short* Brow0 = Bt + (long)(bn + wave * 16 + lr) * 2048 + lc;

    f32x4 acc[4][2];
#pragma unroll
    for (int i = 0; i < 4; i++)
#pragma unroll
        for (int j = 0; j < 2; j++) acc[i][j] = f32x4{0.f, 0.f, 0.f, 0.f};

    auto stage = [&](int b, int step) {
        const int k0 = step * 32;
        load_lds16(Arow0 + k0, &As[b][wave * 16][0]);
        load_lds16(Arow1 + k0, &As[b][wave * 16 + 64][0]);
        load_lds16(Brow0 + k0, &Bs[b][wave * 16][0]);
    };
    auto compute = [&](int b) {
        bf16x8 af[4], bf[2];
#pragma unroll
        for (int s = 0; s < 4; s++)
            af[s] = *(const bf16x8*)&As[b][wm * 64 + s * 16 + (lane & 15)][(lane >> 4) * 8];
#pragma unroll
        for (int t = 0; t < 2; t++)
            bf[t] = *(const bf16x8*)&Bs[b][wn * 32 + t * 16 + (lane & 15)][(lane >> 4) * 8];
#pragma unroll
        for (int s = 0; s < 4; s++)
#pragma unroll
            for (int t = 0; t < 2; t++)
                acc[s][t] = __builtin_amdgcn_mfma_f32_16x16x32_bf16(af[s], bf[t], acc[s][t], 0, 0, 0);
    };
    // One barrier per PAIR of K-steps. Invariants (3 loads/wave/stage, FIFO):
    //  - at pair p entry: stages 2p..2p+3 outstanding (12 loads); vmcnt(6)
    //    retires exactly stages 2p,2p+1 (this pair's buffers).
    //  - barrier => ALL waves' pair-p loads landed; also all waves finished
    //    computing pair p-1 (program order) => staging into pair p-1's freed
    //    buffers ((2p+4)%6 = (2p-2)%6) is safe AFTER the barrier.
    auto pairstep = [&](int ca, int cb, int sa, int sb, int stepA) {
        asm volatile("s_waitcnt vmcnt(6)" ::: "memory");
        __builtin_amdgcn_s_barrier();
        __builtin_amdgcn_sched_barrier(0);
        stage(sa, stepA);
        stage(sb, stepA + 1);
        __builtin_amdgcn_sched_barrier(0);
        compute(ca);
        compute(cb);
    };

    stage(0, 0); stage(1, 1); stage(2, 2); stage(3, 3);
    for (int g = 0; g < 10; ++g) {
        const int b6 = g * 6;
        pairstep(0, 1, 4, 5, b6 + 4);   // compute steps b6+0,b6+1
        pairstep(2, 3, 0, 1, b6 + 6);   // compute steps b6+2,b6+3
        pairstep(4, 5, 2, 3, b6 + 8);   // compute steps b6+4,b6+5
    }
    // epilogue: steps 60..63 outstanding in bufs 0..3
    asm volatile("s_waitcnt vmcnt(6)" ::: "memory");
    __builtin_amdgcn_s_barrier();
    __builtin_amdgcn_sched_barrier(0);
    compute(0); compute(1);            // steps 60,61
    asm volatile("s_waitcnt vmcnt(0)" ::: "memory");
    __builtin_amdgcn_s_barrier();
    __builtin_amdgcn_sched_barrier(0);
    compute(2); compute(3);            // steps 62,63

    // epilogue: C/D layout col=lane&15, row=(lane>>4)*4+reg
    if (kv == 0) {
#pragma unroll
        for (int s = 0; s < 4; s++) {
#pragma unroll
            for (int t = 0; t < 2; t++) {
                const int col  = bn + wn * 32 + t * 16 + (lane & 15);
                const int row0 = bm + wm * 64 + s * 16 + (lane >> 4) * 4;
                const float bb = bq[col];
#pragma unroll
                for (int r = 0; r < 4; r++)
                    Qb[(long)(row0 + r) * 2048 + col] = f2bf(acc[s][t][r] + bb);
            }
        }
    } else {
        const float* bp = (kv == 1) ? bk : bv;
#pragma unroll
        for (int s = 0; s < 4; s++) {
#pragma unroll
            for (int t = 0; t < 2; t++) {
                const int col = bn + wn * 32 + t * 16 + (lane & 15);
                const int dd  = col & 127;
                const float bb = bp[col];
                const int j0 = bm + wm * 64 + s * 16 + (lane >> 4) * 4;
#pragma unroll
                for (int r = 0; r < 4; r++) {
                    const int j = j0 + r;
                    const unsigned short h16 = f2bf(acc[s][t][r] + bb);
                    if (kv == 1) Ksel [h * 32768 + j * 128 + dd] = h16;
                    else         VselT[h * 32768 + dd * 256 + j] = h16;
                }
            }
        }
    }
}

// ---------------------------------------------------------------------------
// O GEMM: out = Att @ WoT^T + bo, fp32 direct write. Tile 128x64, full K=2048,
// 512 blocks (XCD-remapped), depth-3 pipeline + LDS swizzle (round-6 state).
// ---------------------------------------------------------------------------
__global__ __launch_bounds__(256) void gemm_o(
    const unsigned short* __restrict__ Att,   // [2048][2048]
    const unsigned short* __restrict__ WoT,   // [n][k]
    const float* __restrict__ bo,
    float* __restrict__ out)                  // [2048][2048]
{
    __shared__ __align__(16) unsigned short As[4][128][32];
    __shared__ __align__(16) unsigned short Bs[4][64][32];

    const int tid  = threadIdx.x;
    const int lane = tid & 63;
    const int wave = tid >> 6;
    const int wm = wave >> 1, wn = wave & 1;
    const int lr  = lane >> 2;
    const int scc = (((lane & 3) ^ ((lr >> 1) & 3))) * 8;
    const int rc  = (((lane >> 4) ^ (((lane & 15) >> 1) & 3))) * 8;

    const int t0 = blockIdx.x;
    const int tl = (t0 & 7) * 64 + (t0 >> 3);         // XCD-contiguous logical id
    const int st = tl >> 5, u = tl & 31;              // supertile 4x8
    const int bm = ((st >> 2) * 4 + (u >> 3)) * 128;
    const int bn = ((st & 3) * 8 + (u & 7)) * 64;

    const unsigned short* Arow0 = Att + (long)(bm + wave * 16 + lr) * 2048 + scc;
    const unsigned short* Arow1 = Arow0 + 64 * 2048;
    const unsigned short* Brow0 = WoT + (long)(bn + wave * 16 + lr) * 2048 + scc;

    f32x4 acc[4][2];
#pragma unroll
    for (int i = 0; i < 4; i++)
#pragma unroll
        for (int j = 0; j < 2; j++) acc[i][j] = f32x4{0.f, 0.f, 0.f, 0.f};

    auto stage = [&](int b, int step) {
        const int k0 = step * 32;
        load_lds16(Arow0 + k0, &As[b][wave * 16][0]);
        load_lds16(Arow1 + k0, &As[b][wave * 16 + 64][0]);
        load_lds16(Brow0 + k0, &Bs[b][wave * 16][0]);
    };
    auto compute = [&](int b) {
        bf16x8 af[4], bf[2];
#pragma unroll
        for (int s = 0; s < 4; s++)
            af[s] = *(const bf16x8*)&As[b][wm * 64 + s * 16 + (lane & 15)][rc];
#pragma unroll
        for (int t = 0; t < 2; t++)
            bf[t] = *(const bf16x8*)&Bs[b][wn * 32 + t * 16 + (lane & 15)][rc];
#pragma unroll
        for (int s = 0; s < 4; s++)
#pragma unroll
            for (int t = 0; t < 2; t++)
                acc[s][t] = __builtin_amdgcn_mfma_f32_16x16x32_bf16(af[s], bf[t], acc[s][t], 0, 0, 0);
    };

    stage(0, 0);
    stage(1, 1);
    stage(2, 2);
#pragma unroll 4
    for (int t = 0; t < 61; ++t) {
        asm volatile("s_waitcnt vmcnt(6)" ::: "memory");
        __builtin_amdgcn_s_barrier();
        __builtin_amdgcn_sched_barrier(0);
        stage((t + 3) & 3, t + 3);
        __builtin_amdgcn_sched_barrier(0);
        compute(t & 3);
    }
    asm volatile("s_waitcnt vmcnt(6)" ::: "memory");
    __builtin_amdgcn_s_barrier();
    __builtin_amdgcn_sched_barrier(0);
    compute(1);                        // t=61
    asm volatile("s_waitcnt vmcnt(3)" ::: "memory");
    __builtin_amdgcn_s_barrier();
    __builtin_amdgcn_sched_barrier(0);
    compute(2);                        // t=62
    asm volatile("s_waitcnt vmcnt(0)" ::: "memory");
    __builtin_amdgcn_s_barrier();
    __builtin_amdgcn_sched_barrier(0);
    compute(3);                        // t=63

#pragma unroll
    for (int s = 0; s < 4; s++) {
#pragma unroll
        for (int t = 0; t < 2; t++) {
            const int col  = bn + wn * 32 + t * 16 + (lane & 15);
            const int row0 = bm + wm * 64 + s * 16 + (lane >> 4) * 4;
            const float bb = bo[col];
#pragma unroll
            for (int r = 0; r < 4; r++)
                out[(long)(row0 + r) * 2048 + col] = acc[s][t][r] + bb;
        }
    }
}

// ---------------------------------------------------------------------------
// Fused attention, 64-query tiles (round-6 state: XOR chunk swizzle on Q/K/V).
// ---------------------------------------------------------------------------
#define QS_OFF(c)  ((c) * 2048)
#define KS_OFF(c)  (4096 + (c) * 8192)
#define PS_OFF     0
#define VS_OFF(c)  (16896 + (c) * 4096)

__global__ __launch_bounds__(256, 2) void attn_kernel(
    const unsigned short* __restrict__ Qb,     // [2048][2048] (token, h*128+d)
    const unsigned short* __restrict__ Ksel,   // [16][256][128]
    const unsigned short* __restrict__ VselT,  // [16][128][256]
    unsigned short* __restrict__ Att)          // [2048][2048]
{
    __shared__ __align__(16) unsigned short smem[25088];   // 50176 B
    __shared__ float linv[64];

    const int tid  = threadIdx.x;
    const int lane = tid & 63;
    const int wave = tid >> 6;
    const int bm = blockIdx.x * 64;
    const int h  = blockIdx.y;
    const int lr  = lane >> 2;
    const int scc = (((lane & 3) ^ ((lr >> 1) & 3))) * 8;
    const int rc  = (((lane >> 4) ^ (((lane & 15) >> 1) & 3))) * 8;

    const unsigned short* Kh = Ksel  + h * 32768;
    const unsigned short* Vh = VselT + h * 32768;

    // ---- phase 1: S tile 64x256, wave owns rows [wave*16, +16)
    f32x4 acc[16];
#pragma unroll
    for (int t = 0; t < 16; t++) acc[t] = f32x4{0.f, 0.f, 0.f, 0.f};

#pragma unroll
    for (int c2 = 0; c2 < 2; c2++) {           // d-chunks of 64
        __syncthreads();
#pragma unroll
        for (int c = 0; c < 2; c++) {          // 32-wide sub-chunks
            const int k0 = c2 * 64 + c * 32;
            // Q: 64 rows, 1 wave-load per wave (16 rows each)
            load_lds16(Qb + (long)(bm + wave * 16 + lr) * 2048 + h * 128 + k0 + scc,
                       &smem[QS_OFF(c) + wave * 512]);
            // K: 256 rows, 4 wave-loads per wave
#pragma unroll
            for (int q = 0; q < 4; q++)
                load_lds16(Kh + (wave * 64 + q * 16 + lr) * 128 + k0 + scc,
                           &smem[KS_OFF(c) + (wave * 64 + q * 16) * 32]);
        }
        __syncthreads();
#pragma unroll
        for (int kk = 0; kk < 2; kk++) {
            bf16x8 af = *(const bf16x8*)&smem[QS_OFF(kk) + (wave * 16 + (lane & 15)) * 32 + rc];
#pragma unroll
            for (int t = 0; t < 16; t++) {
                bf16x8 bfv = *(const bf16x8*)&smem[KS_OFF(kk) + (t * 16 + (lane & 15)) * 32 + rc];
                acc[t] = __builtin_amdgcn_mfma_f32_16x16x32_bf16(af, bfv, acc[t], 0, 0, 0);
            }
        }
    }
    __syncthreads();   // all Q/K frag reads done -> region reusable for Ps/Vs

    // ---- phase 2: in-wave softmax over 256 cols; P = exp(scale*(s-max)), bf16
    const float se = 0.08838834764831845f * 1.4426950408889634f;  // scale*log2(e)
#pragma unroll
    for (int r = 0; r < 4; r++) {
        float mx = -3.0e38f;
#pragma unroll
        for (int t = 0; t < 16; t++) mx = fmaxf(mx, acc[t][r]);
#pragma unroll
        for (int off = 1; off < 16; off <<= 1) mx = fmaxf(mx, __shfl_xor(mx, off));
        float sum = 0.f;
#pragma unroll
        for (int t = 0; t < 16; t++) {
            float p = exp2f((acc[t][r] - mx) * se);
            acc[t][r] = p;
            sum += p;
        }
#pragma unroll
        for (int off = 1; off < 16; off <<= 1) sum += __shfl_xor(sum, off);
        const int row = wave * 16 + (lane >> 4) * 4 + r;
#pragma unroll
        for (int t = 0; t < 16; t++)
            smem[PS_OFF + row * 264 + t * 16 + (lane & 15)] = f2bf(acc[t][r]);
        if ((lane & 15) == 0) linv[row] = 1.0f / sum;
    }

    // ---- phase 3: O = P @ Vsel, 2x2 waves over 64x128; stage 2 V chunks/iter
    const int wm2 = wave >> 1, wn2 = wave & 1;
    f32x4 acc2[2][4];
#pragma unroll
    for (int i = 0; i < 2; i++)
#pragma unroll
        for (int j = 0; j < 4; j++) acc2[i][j] = f32x4{0.f, 0.f, 0.f, 0.f};

#pragma unroll
    for (int c2 = 0; c2 < 4; c2++) {           // j-chunks of 64
        // stage Vs chunks (region disjoint from Ps; phase1 drained by barrier above)
#pragma unroll
        for (int c = 0; c < 2; c++) {
            const int j0 = c2 * 64 + c * 32;
#pragma unroll
            for (int q = 0; q < 2; q++)
                load_lds16(Vh + (wave * 32 + q * 16 + lr) * 256 + j0 + scc,
                           &smem[VS_OFF(c) + (wave * 32 + q * 16) * 32]);
        }
        __syncthreads();   // staged V + (first iter) Ps visible
#pragma unroll
        for (int c = 0; c < 2; c++) {
            const int j0 = c2 * 64 + c * 32;
            bf16x8 af2[2], bf2v[4];
#pragma unroll
            for (int s2 = 0; s2 < 2; s2++)
                af2[s2] = *(const bf16x8*)&smem[PS_OFF + (wm2 * 32 + s2 * 16 + (lane & 15)) * 264 + j0 + (lane >> 4) * 8];
#pragma unroll
            for (int t2 = 0; t2 < 4; t2++)
                bf2v[t2] = *(const bf16x8*)&smem[VS_OFF(c) + (wn2 * 64 + t2 * 16 + (lane & 15)) * 32 + rc];
#pragma unroll
            for (int s2 = 0; s2 < 2; s2++)
#pragma unroll
                for (int t2 = 0; t2 < 4; t2++)
                    acc2[s2][t2] = __builtin_amdgcn_mfma_f32_16x16x32_bf16(af2[s2], bf2v[t2], acc2[s2][t2], 0, 0, 0);
        }
        __syncthreads();   // V frag reads done before next stage overwrites
    }

    // ---- epilogue: divide by row sum, write Att[token][h*128+d]
#pragma unroll
    for (int s2 = 0; s2 < 2; s2++) {
#pragma unroll
        for (int t2 = 0; t2 < 4; t2++) {
            const int d = wn2 * 64 + t2 * 16 + (lane & 15);
#pragma unroll
            for (int r = 0; r < 4; r++) {
                const int row = wm2 * 32 + s2 * 16 + (lane >> 4) * 4 + r;
                float v = acc2[s2][t2][r] * linv[row];
                Att[(long)(bm + row) * 2048 + h * 128 + d] = f2bf(v);
            }
        }
    }
}

// ---------------------------------------------------------------------------
// prep: blocks [0,4096): fp32->bf16 transposed weights, 64x64 tiles (4 mats);
//       blocks [4096,4608): colsum partials of hs (ranking stage 1)
// ---------------------------------------------------------------------------
__global__ __launch_bounds__(256) void prep_kernel(Ptr4 srcs, unsigned short* __restrict__ WT4,
                                                   const float* __restrict__ hs,
                                                   double* __restrict__ part) {
    const int b = blockIdx.x;
    const int tid = threadIdx.x;
    if (b < 4096) {
        __shared__ float tile[64][65];
        const int z = b >> 10, xy = b & 1023;
        const float* W = srcs.p[z];
        unsigned short* WT = WT4 + (long)z * 4194304;
        const int bx = (xy & 31) * 64;   // n
        const int by = (xy >> 5) * 64;   // k
        const int x = tid & 63, y = tid >> 6;   // y in 0..3
#pragma unroll
        for (int i = 0; i < 64; i += 4)
            tile[y + i][x] = W[(long)(by + y + i) * 2048 + bx + x];
        __syncthreads();
#pragma unroll
        for (int i = 0; i < 64; i += 4)
            WT[(long)(bx + y + i) * 2048 + by + x] = f2bf(tile[x][y + i]);
    } else {
        const int c = b - 4096;                  // 0..511
        const int col = (c & 7) * 256 + tid;
        const int r0  = (c >> 3) * 32;
        double a = 0.0;
#pragma unroll 4
        for (int r = 0; r < 32; r++) a += (double)hs[(long)(r0 + r) * 2048 + col];
        part[(long)(c >> 3) * 2048 + col] = a;
    }
}

__global__ void fill_kernel(float* p, float v, long n) {
    long i = ((long)blockIdx.x * blockDim.x + threadIdx.x) * 4;
    if (i + 3 < n) { p[i] = v; p[i+1] = v; p[i+2] = v; p[i+3] = v; }
}

// ---------------------------------------------------------------------------
// Ranking path
// ---------------------------------------------------------------------------
__global__ __launch_bounds__(256) void mean_qsum_part(const double* __restrict__ part,
                                                      const float* __restrict__ Wq,
                                                      double* __restrict__ partq) {
    __shared__ float hsb[32];
    const int j  = blockIdx.x * 256 + threadIdx.x;
    const int i0 = blockIdx.y * 32;
    if (threadIdx.x < 32) {
        double s = 0.0;
#pragma unroll 4
        for (int g = 0; g < 64; g++) s += part[(long)g * 2048 + i0 + threadIdx.x];
        hsb[threadIdx.x] = (float)(s * (1.0 / 2048.0));
    }
    __syncthreads();
    double a = 0.0;
#pragma unroll 4
    for (int r = 0; r < 32; r++)
        a += (double)hsb[r] * (double)Wq[(long)(i0 + r) * 2048 + j];
    partq[(long)blockIdx.y * 2048 + j] = a;
}

__global__ void qsum_fin(const double* __restrict__ partq, const float* __restrict__ bq,
                         float* __restrict__ qbar) {
    const int j = blockIdx.x * 64 + threadIdx.x;
    double s = (double)bq[j];
#pragma unroll 4
    for (int g = 0; g < 64; g++) s += partq[(long)g * 2048 + j];
    qbar[j] = (float)s;
}

__global__ __launch_bounds__(256) void u_kernel(const float* __restrict__ Wk,
                                                const float* __restrict__ qbar,
                                                float* __restrict__ U) {
    const int i = blockIdx.x, t = threadIdx.x;
#pragma unroll
    for (int r = 0; r < 2; r++) {
        const int e = r * 1024 + t * 4;
        float4 w = *(const float4*)(Wk + (long)i * 2048 + e);
        float4 q = *(const float4*)(qbar + e);
        float a = w.x * q.x + w.y * q.y + w.z * q.z + w.w * q.w;
#pragma unroll
        for (int off = 16; off; off >>= 1) a += __shfl_xor(a, off);
        if ((t & 31) == 0) U[(long)i * 16 + r * 8 + (t >> 5)] = a;
    }
}

// ---------------------------------------------------------------------------
// fused: HSb = bf16(hs row) AND imp[h,m] = hs[m,:] . U[:,h], 4 rows/block.
// Register-resident, float4-vectorized; accumulation order matches the
// original scalar version -> imp bit-identical -> identical top-k selection.
// ---------------------------------------------------------------------------
__global__ __launch_bounds__(256) void cast_imp_kernel(const float* __restrict__ hs,
                                                       const float* __restrict__ U,
                                                       unsigned short* __restrict__ HSb,
                                                       float* __restrict__ imp) {
    __shared__ float red[4][4][16];            // [wavegroup][row][head]
    const int m0 = blockIdx.x * 4, t = threadIdx.x;

    float va[4][8];
#pragma unroll
    for (int r = 0; r < 4; r++) {
        const float4 v0 = *(const float4*)(hs + (long)(m0 + r) * 2048 + t * 8);
        const float4 v1 = *(const float4*)(hs + (long)(m0 + r) * 2048 + t * 8 + 4);
        va[r][0] = v0.x; va[r][1] = v0.y; va[r][2] = v0.z; va[r][3] = v0.w;
        va[r][4] = v1.x; va[r][5] = v1.y; va[r][6] = v1.z; va[r][7] = v1.w;
        u16x8 hb;
#pragma unroll
        for (int j = 0; j < 8; j++) hb[j] = f2bf(va[r][j]);
        *(u16x8*)(HSb + (long)(m0 + r) * 2048 + t * 8) = hb;
    }

    float p[4][16];
#pragma unroll
    for (int r = 0; r < 4; r++)
#pragma unroll
        for (int h = 0; h < 16; h++) p[r][h] = 0.f;

    const float4* Uq = (const float4*)(U + (long)t * 128);   // rows t*8..t*8+8
#pragma unroll
    for (int j = 0; j < 8; j++) {
        const float4 u0 = Uq[j * 4 + 0];
        const float4 u1 = Uq[j * 4 + 1];
        const float4 u2 = Uq[j * 4 + 2];
        const float4 u3 = Uq[j * 4 + 3];
#pragma unroll
        for (int r = 0; r < 4; r++) {
            const float v = va[r][j];
            p[r][0]  += v * u0.x; p[r][1]  += v * u0.y; p[r][2]  += v * u0.z; p[r][3]  += v * u0.w;
            p[r][4]  += v * u1.x; p[r][5]  += v * u1.y; p[r][6]  += v * u1.z; p[r][7]  += v * u1.w;
            p[r][8]  += v * u2.x; p[r][9]  += v * u2.y; p[r][10] += v * u2.z; p[r][11] += v * u2.w;
            p[r][12] += v * u3.x; p[r][13] += v * u3.y; p[r][14] += v * u3.z; p[r][15] += v * u3.w;
        }
    }

#pragma unroll
    for (int off = 32; off; off >>= 1)
#pragma unroll
        for (int r = 0; r < 4; r++)
#pragma unroll
            for (int h = 0; h < 16; h++) p[r][h] += __shfl_down(p[r][h], off);
    if ((t & 63) == 0)
#pragma unroll
        for (int r = 0; r < 4; r++)
#pragma unroll
            for (int h = 0; h < 16; h++) red[t >> 6][r][h] = p[r][h];
    __syncthreads();
    if (t < 64) {
        const int h = t & 15, r = t >> 4;
        imp[(long)h * 2048 + m0 + r] =
            red[0][r][h] + red[1][r][h] + red[2][r][h] + red[3][r][h];
    }
}

// ---------------------------------------------------------------------------
// exact top-256 per head, emitting FORWARD map idx[h][rank] = token.
// ---------------------------------------------------------------------------
__global__ __launch_bounds__(64) void topk_idx(const float* __restrict__ imp,
                                               int* __restrict__ idx) {
    const int h = blockIdx.x;
    const int lane = threadIdx.x;
    unsigned u[32];
#pragma unroll
    for (int r = 0; r < 32; r++) {
        unsigned x = __float_as_uint(imp[(long)h * 2048 + r * 64 + lane]);
        u[r] = (x & 0x80000000u) ? ~x : (x | 0x80000000u);
    }
    unsigned cur = 0;
    for (int b = 31; b >= 0; b--) {
        const unsigned cand = cur | (1u << b);
        int tot = 0;
#pragma unroll
        for (int r = 0; r < 32; r++)
            tot += (int)__popcll(__ballot(u[r] >= cand));
        if (tot >= 256) cur = cand;
    }
    const unsigned long long below = (1ull << lane) - 1ull;
    int pos[32];
    int base = 0;
#pragma unroll
    for (int r = 0; r < 32; r++) {
        const bool q = u[r] > cur;
        const unsigned long long m = __ballot(q);
        pos[r] = q ? base + (int)__popcll(m & below) : -1;
        base += (int)__popcll(m);
    }
    // ties at threshold continue from the strict count
#pragma unroll
    for (int r = 0; r < 32; r++) {
        const bool q = (u[r] == cur);
        const unsigned long long m = __ballot(q);
        if (q) {
            const int p = base + (int)__popcll(m & below);
            pos[r] = (p < 256) ? p : -1;
        }
        base += (int)__popcll(m);
    }
#pragma unroll
    for (int r = 0; r < 32; r++)
        if (pos[r] >= 0) idx[h * 256 + pos[r]] = r * 64 + lane;
}

// ---------------------------------------------------------------------------
extern "C" void kernel_launch(void* const* d_in, const int* in_sizes, int n_in,
                              void* d_out, int out_size, void* d_ws, size_t ws_size,
                              hipStream_t stream)
{
    const float* hs = (const float*)d_in[0];
    const float* Wq = (const float*)d_in[1];
    const float* bq = (const float*)d_in[2];
    const float* Wk = (const float*)d_in[3];
    const float* bk = (const float*)d_in[4];
    const float* Wv = (const float*)d_in[5];
    const float* bv = (const float*)d_in[6];
    const float* Wo = (const float*)d_in[7];
    const float* bo = (const float*)d_in[8];

    char* ws = (char*)d_ws;
    size_t off = 0;
    auto alloc = [&](size_t b) -> void* {
        void* p = ws + off;
        off = (off + b + 255) & ~(size_t)255;
        return p;
    };
    unsigned short* HSb   = (unsigned short*)alloc(8388608);     // 2048x2048 bf16
    unsigned short* WT4   = (unsigned short*)alloc(4 * 8388608); // WqT|WkT|WvT|WoT
    unsigned short* Qb    = (unsigned short*)alloc(8388608);     // Q [2048][2048]
    unsigned short* Att   = (unsigned short*)alloc(8388608);
    unsigned short* Ksel  = (unsigned short*)alloc(1048576);     // [16][256][128]
    unsigned short* VselT = (unsigned short*)alloc(1048576);     // [16][128][256]
    double* part  = (double*)alloc(1048576);                     // [64][2048]
    double* partq = (double*)alloc(1048576);                     // [64][2048]
    float* qbar  = (float*)alloc(8192);
    float* U     = (float*)alloc(131072);                        // [2048][16]
    float* imp   = (float*)alloc(131072);                        // [16][2048]
    int*   idx   = (int*)alloc(16384);                           // [16][256]

    if (off > ws_size) {
        fill_kernel<<<4096, 256, 0, stream>>>((float*)d_out, 12345.0f, (long)out_size);
        return;
    }

    unsigned short* WoT = WT4 + 3 * 4194304;

    // 1. weight transposes (64x64 tiles) + colsum partials (fused)
    prep_kernel<<<4608, 256, 0, stream>>>(Ptr4{{Wq, Wk, Wv, Wo}}, WT4, hs, part);

    // 2-5. ranking chain (exact, deterministic)
    mean_qsum_part<<<dim3(8, 64), 256, 0, stream>>>(part, Wq, partq);
    qsum_fin<<<32, 64, 0, stream>>>(partq, bq, qbar);
    u_kernel<<<2048, 256, 0, stream>>>(Wk, qbar, U);
    cast_imp_kernel<<<512, 256, 0, stream>>>(hs, U, HSb, imp);

    // 6. top-256 per head -> forward map idx[h][rank] = token
    topk_idx<<<16, 64, 0, stream>>>(imp, idx);

    // 7. combined QKV: 128 gathered-KV blocks (first) + 512 Q blocks (128x64)
    gemm_qkv<<<640, 256, 0, stream>>>(HSb, WT4, bq, bk, bv, idx, Qb, Ksel, VselT);

    // 8. fused attention: S, softmax, PV  (64-query tiles)
    attn_kernel<<<dim3(32, 16), 256, 0, stream>>>(Qb, Ksel, VselT, Att);

    // 9. O GEMM full-K, 128x64 tiles, direct fp32 write with bias
    gemm_o<<<512, 256, 0, stream>>>(Att, WoT, bo, (float*)d_out);
}

// Round 9
// 277.576 us; speedup vs baseline: 1.0284x; 1.0284x over previous
//
#include <hip/hip_runtime.h>

// ---------------------------------------------------------------------------
// SparseAttention on MI355X (gfx950)
// hidden=2048, heads=16, d=128, topk=256, N=2048, B=1
//
// Ranking path (fp32/fp64, exact):  imp[h,m] = hs[m,:] . U[:,h]
// K/V computed gather-first (256 selected rows per head).
// gemm_qkv: best-measured config (R5): 128x64 tiles, 640 blocks, depth-3
//   counted-vmcnt pipeline (4 LDS bufs, 48KB -> 3 blocks/CU), plain
//   addressing. Measured A/B: LDS swizzle, XCD remap, and paired barriers
//   each cost >= as much as they save here (occupancy/critical-path regime).
// gemm_o / attn: best-measured config (R6): XOR chunk swizzle (conflicts=0)
//   + XCD remap on gemm_o.
// ---------------------------------------------------------------------------

typedef __attribute__((ext_vector_type(8))) short bf16x8;
typedef __attribute__((ext_vector_type(8))) unsigned short u16x8;
typedef __attribute__((ext_vector_type(4))) float f32x4;

__device__ __forceinline__ unsigned short f2bf(float x) {
    unsigned u = __float_as_uint(x);
    u += 0x7fffu + ((u >> 16) & 1u);      // round to nearest even
    return (unsigned short)(u >> 16);
}

__device__ __forceinline__ void load_lds16(const unsigned short* g, unsigned short* l) {
    __builtin_amdgcn_global_load_lds(
        (const __attribute__((address_space(1))) unsigned int*)g,
        (__attribute__((address_space(3))) unsigned int*)l,
        16, 0, 0);
}

struct Ptr4  { const float* p[4]; };

// ---------------------------------------------------------------------------
// Combined QKV GEMM, tile 128x64, BK=32, 256 threads (2x2 waves), 640 blocks.
// bid <  128: gathered K/V block (h, j-tile, d-tile decode).
// bid >= 128: Q block, 4x8 supertiled. Writes Qb (+bq), bf16.
// Depth-3 pipeline: 4 LDS buffers, 3 loads/wave/stage, vmcnt(6) + raw barrier.
// ---------------------------------------------------------------------------
__global__ __launch_bounds__(256) void gemm_qkv(
    const unsigned short* __restrict__ HSb,   // [2048][2048] bf16
    const unsigned short* __restrict__ WT4,   // WqT|WkT|WvT|WoT, each [n][k] bf16
    const float* __restrict__ bq,
    const float* __restrict__ bk,
    const float* __restrict__ bv,
    const int* __restrict__ idx,              // [16][256] forward map
    unsigned short* __restrict__ Qb,          // [2048][2048]
    unsigned short* __restrict__ Ksel,        // [16][256][128]
    unsigned short* __restrict__ VselT)       // [16][128][256]
{
    __shared__ __align__(16) unsigned short As[4][128][32];   // 32 KB
    __shared__ __align__(16) unsigned short Bs[4][64][32];    // 16 KB

    const int tid  = threadIdx.x;
    const int lane = tid & 63;
    const int wave = tid >> 6;
    const int wm = wave >> 1, wn = wave & 1;
    const int lr = lane >> 2;          // 0..15 row within 16-row staging group
    const int lc = (lane & 3) * 8;     // bf16 col offset (16B chunk)

    const int bid = blockIdx.x;

    int kv, h = 0, bm, bn;
    const unsigned short* Bt;
    long ar0, ar1;                     // global A rows for this lane's two stages
    if (bid < 128) {
        kv = 1 + (bid >> 6);                        // 1=K, 2=V
        const int t = bid & 63;
        h  = t >> 2;
        bm = ((t >> 1) & 1) * 128;                  // j-tile base within head
        bn = h * 128 + (t & 1) * 64;                // d-tile base in WT row space
        Bt = WT4 + (long)kv * 4194304;
        ar0 = idx[h * 256 + bm + wave * 16 + lr];
        ar1 = idx[h * 256 + bm + wave * 16 + 64 + lr];
    } else {
        kv = 0;
        const int t = bid - 128;
        const int st = t >> 5, u = t & 31;          // supertile: 4 M-tiles x 8 N-tiles
        bm = ((st >> 2) * 4 + (u >> 3)) * 128;
        bn = ((st & 3) * 8 + (u & 7)) * 64;
        Bt = WT4;                                   // WqT
        ar0 = bm + wave * 16 + lr;
        ar1 = ar0 + 64;
    }

    const unsigned short* Arow0 = HSb + ar0 * 2048 + lc;
    const unsigned short* Arow1 = HSb + ar1 * 2048 + lc;
    const unsigned short* Brow0 = Bt + (long)(bn + wave * 16 + lr) * 2048 + lc;

    f32x4 acc[4][2];
#pragma unroll
    for (int i = 0; i < 4; i++)
#pragma unroll
        for (int j = 0; j < 2; j++) acc[i][j] = f32x4{0.f, 0.f, 0.f, 0.f};

    auto stage = [&](int b, int step) {
        const int k0 = step * 32;
        load_lds16(Arow0 + k0, &As[b][wave * 16][0]);
        load_lds16(Arow1 + k0, &As[b][wave * 16 + 64][0]);
        load_lds16(Brow0 + k0, &Bs[b][wave * 16][0]);
    };
    auto compute = [&](int b) {
        bf16x8 af[4], bf[2];
#pragma unroll
        for (int s = 0; s < 4; s++)
            af[s] = *(const bf16x8*)&As[b][wm * 64 + s * 16 + (lane & 15)][(lane >> 4) * 8];
#pragma unroll
        for (int t = 0; t < 2; t++)
            bf[t] = *(const bf16x8*)&Bs[b][wn * 32 + t * 16 + (lane & 15)][(lane >> 4) * 8];
#pragma unroll
        for (int s = 0; s < 4; s++)
#pragma unroll
            for (int t = 0; t < 2; t++)
                acc[s][t] = __builtin_amdgcn_mfma_f32_16x16x32_bf16(af[s], bf[t], acc[s][t], 0, 0, 0);
    };

    // Pipeline invariants (3 loads per wave per stage):
    //  - at iter t, stages t..t+2 outstanding (9 loads); vmcnt(6) retires stage t.
    //  - s_barrier after the wait => ALL waves' stage-t loads landed.
    //  - stage(t+3) overwrites buf[(t-1)&3], whose readers finished before the
    //    barrier of iteration t.
    stage(0, 0);
    stage(1, 1);
    stage(2, 2);
#pragma unroll 4
    for (int t = 0; t < 61; ++t) {
        asm volatile("s_waitcnt vmcnt(6)" ::: "memory");
        __builtin_amdgcn_s_barrier();
        __builtin_amdgcn_sched_barrier(0);
        stage((t + 3) & 3, t + 3);
        __builtin_amdgcn_sched_barrier(0);
        compute(t & 3);
    }
    asm volatile("s_waitcnt vmcnt(6)" ::: "memory");
    __builtin_amdgcn_s_barrier();
    __builtin_amdgcn_sched_barrier(0);
    compute(1);                        // t=61
    asm volatile("s_waitcnt vmcnt(3)" ::: "memory");
    __builtin_amdgcn_s_barrier();
    __builtin_amdgcn_sched_barrier(0);
    compute(2);                        // t=62
    asm volatile("s_waitcnt vmcnt(0)" ::: "memory");
    __builtin_amdgcn_s_barrier();
    __builtin_amdgcn_sched_barrier(0);
    compute(3);                        // t=63

    // epilogue: C/D layout col=lane&15, row=(lane>>4)*4+reg
    if (kv == 0) {
#pragma unroll
        for (int s = 0; s < 4; s++) {
#pragma unroll
            for (int t = 0; t < 2; t++) {
                const int col  = bn + wn * 32 + t * 16 + (lane & 15);
                const int row0 = bm + wm * 64 + s * 16 + (lane >> 4) * 4;
                const float bb = bq[col];
#pragma unroll
                for (int r = 0; r < 4; r++)
                    Qb[(long)(row0 + r) * 2048 + col] = f2bf(acc[s][t][r] + bb);
            }
        }
    } else {
        const float* bp = (kv == 1) ? bk : bv;
#pragma unroll
        for (int s = 0; s < 4; s++) {
#pragma unroll
            for (int t = 0; t < 2; t++) {
                const int col = bn + wn * 32 + t * 16 + (lane & 15);
                const int dd  = col & 127;
                const float bb = bp[col];
                const int j0 = bm + wm * 64 + s * 16 + (lane >> 4) * 4;
#pragma unroll
                for (int r = 0; r < 4; r++) {
                    const int j = j0 + r;
                    const unsigned short h16 = f2bf(acc[s][t][r] + bb);
                    if (kv == 1) Ksel [h * 32768 + j * 128 + dd] = h16;
                    else         VselT[h * 32768 + dd * 256 + j] = h16;
                }
            }
        }
    }
}

// ---------------------------------------------------------------------------
// O GEMM: out = Att @ WoT^T + bo, fp32 direct write. Tile 128x64, full K=2048,
// 512 blocks (XCD-remapped), depth-3 pipeline + LDS swizzle (R6 state).
// ---------------------------------------------------------------------------
__global__ __launch_bounds__(256) void gemm_o(
    const unsigned short* __restrict__ Att,   // [2048][2048]
    const unsigned short* __restrict__ WoT,   // [n][k]
    const float* __restrict__ bo,
    float* __restrict__ out)                  // [2048][2048]
{
    __shared__ __align__(16) unsigned short As[4][128][32];
    __shared__ __align__(16) unsigned short Bs[4][64][32];

    const int tid  = threadIdx.x;
    const int lane = tid & 63;
    const int wave = tid >> 6;
    const int wm = wave >> 1, wn = wave & 1;
    const int lr  = lane >> 2;
    const int scc = (((lane & 3) ^ ((lr >> 1) & 3))) * 8;
    const int rc  = (((lane >> 4) ^ (((lane & 15) >> 1) & 3))) * 8;

    const int t0 = blockIdx.x;
    const int tl = (t0 & 7) * 64 + (t0 >> 3);         // XCD-contiguous logical id
    const int st = tl >> 5, u = tl & 31;              // supertile 4x8
    const int bm = ((st >> 2) * 4 + (u >> 3)) * 128;
    const int bn = ((st & 3) * 8 + (u & 7)) * 64;

    const unsigned short* Arow0 = Att + (long)(bm + wave * 16 + lr) * 2048 + scc;
    const unsigned short* Arow1 = Arow0 + 64 * 2048;
    const unsigned short* Brow0 = WoT + (long)(bn + wave * 16 + lr) * 2048 + scc;

    f32x4 acc[4][2];
#pragma unroll
    for (int i = 0; i < 4; i++)
#pragma unroll
        for (int j = 0; j < 2; j++) acc[i][j] = f32x4{0.f, 0.f, 0.f, 0.f};

    auto stage = [&](int b, int step) {
        const int k0 = step * 32;
        load_lds16(Arow0 + k0, &As[b][wave * 16][0]);
        load_lds16(Arow1 + k0, &As[b][wave * 16 + 64][0]);
        load_lds16(Brow0 + k0, &Bs[b][wave * 16][0]);
    };
    auto compute = [&](int b) {
        bf16x8 af[4], bf[2];
#pragma unroll
        for (int s = 0; s < 4; s++)
            af[s] = *(const bf16x8*)&As[b][wm * 64 + s * 16 + (lane & 15)][rc];
#pragma unroll
        for (int t = 0; t < 2; t++)
            bf[t] = *(const bf16x8*)&Bs[b][wn * 32 + t * 16 + (lane & 15)][rc];
#pragma unroll
        for (int s = 0; s < 4; s++)
#pragma unroll
            for (int t = 0; t < 2; t++)
                acc[s][t] = __builtin_amdgcn_mfma_f32_16x16x32_bf16(af[s], bf[t], acc[s][t], 0, 0, 0);
    };

    stage(0, 0);
    stage(1, 1);
    stage(2, 2);
#pragma unroll 4
    for (int t = 0; t < 61; ++t) {
        asm volatile("s_waitcnt vmcnt(6)" ::: "memory");
        __builtin_amdgcn_s_barrier();
        __builtin_amdgcn_sched_barrier(0);
        stage((t + 3) & 3, t + 3);
        __builtin_amdgcn_sched_barrier(0);
        compute(t & 3);
    }
    asm volatile("s_waitcnt vmcnt(6)" ::: "memory");
    __builtin_amdgcn_s_barrier();
    __builtin_amdgcn_sched_barrier(0);
    compute(1);                        // t=61
    asm volatile("s_waitcnt vmcnt(3)" ::: "memory");
    __builtin_amdgcn_s_barrier();
    __builtin_amdgcn_sched_barrier(0);
    compute(2);                        // t=62
    asm volatile("s_waitcnt vmcnt(0)" ::: "memory");
    __builtin_amdgcn_s_barrier();
    __builtin_amdgcn_sched_barrier(0);
    compute(3);                        // t=63

#pragma unroll
    for (int s = 0; s < 4; s++) {
#pragma unroll
        for (int t = 0; t < 2; t++) {
            const int col  = bn + wn * 32 + t * 16 + (lane & 15);
            const int row0 = bm + wm * 64 + s * 16 + (lane >> 4) * 4;
            const float bb = bo[col];
#pragma unroll
            for (int r = 0; r < 4; r++)
                out[(long)(row0 + r) * 2048 + col] = acc[s][t][r] + bb;
        }
    }
}

// ---------------------------------------------------------------------------
// Fused attention, 64-query tiles (R6 state: XOR chunk swizzle on Q/K/V).
// ---------------------------------------------------------------------------
#define QS_OFF(c)  ((c) * 2048)
#define KS_OFF(c)  (4096 + (c) * 8192)
#define PS_OFF     0
#define VS_OFF(c)  (16896 + (c) * 4096)

__global__ __launch_bounds__(256, 2) void attn_kernel(
    const unsigned short* __restrict__ Qb,     // [2048][2048] (token, h*128+d)
    const unsigned short* __restrict__ Ksel,   // [16][256][128]
    const unsigned short* __restrict__ VselT,  // [16][128][256]
    unsigned short* __restrict__ Att)          // [2048][2048]
{
    __shared__ __align__(16) unsigned short smem[25088];   // 50176 B
    __shared__ float linv[64];

    const int tid  = threadIdx.x;
    const int lane = tid & 63;
    const int wave = tid >> 6;
    const int bm = blockIdx.x * 64;
    const int h  = blockIdx.y;
    const int lr  = lane >> 2;
    const int scc = (((lane & 3) ^ ((lr >> 1) & 3))) * 8;
    const int rc  = (((lane >> 4) ^ (((lane & 15) >> 1) & 3))) * 8;

    const unsigned short* Kh = Ksel  + h * 32768;
    const unsigned short* Vh = VselT + h * 32768;

    // ---- phase 1: S tile 64x256, wave owns rows [wave*16, +16)
    f32x4 acc[16];
#pragma unroll
    for (int t = 0; t < 16; t++) acc[t] = f32x4{0.f, 0.f, 0.f, 0.f};

#pragma unroll
    for (int c2 = 0; c2 < 2; c2++) {           // d-chunks of 64
        __syncthreads();
#pragma unroll
        for (int c = 0; c < 2; c++) {          // 32-wide sub-chunks
            const int k0 = c2 * 64 + c * 32;
            // Q: 64 rows, 1 wave-load per wave (16 rows each)
            load_lds16(Qb + (long)(bm + wave * 16 + lr) * 2048 + h * 128 + k0 + scc,
                       &smem[QS_OFF(c) + wave * 512]);
            // K: 256 rows, 4 wave-loads per wave
#pragma unroll
            for (int q = 0; q < 4; q++)
                load_lds16(Kh + (wave * 64 + q * 16 + lr) * 128 + k0 + scc,
                           &smem[KS_OFF(c) + (wave * 64 + q * 16) * 32]);
        }
        __syncthreads();
#pragma unroll
        for (int kk = 0; kk < 2; kk++) {
            bf16x8 af = *(const bf16x8*)&smem[QS_OFF(kk) + (wave * 16 + (lane & 15)) * 32 + rc];
#pragma unroll
            for (int t = 0; t < 16; t++) {
                bf16x8 bfv = *(const bf16x8*)&smem[KS_OFF(kk) + (t * 16 + (lane & 15)) * 32 + rc];
                acc[t] = __builtin_amdgcn_mfma_f32_16x16x32_bf16(af, bfv, acc[t], 0, 0, 0);
            }
        }
    }
    __syncthreads();   // all Q/K frag reads done -> region reusable for Ps/Vs

    // ---- phase 2: in-wave softmax over 256 cols; P = exp(scale*(s-max)), bf16
    const float se = 0.08838834764831845f * 1.4426950408889634f;  // scale*log2(e)
#pragma unroll
    for (int r = 0; r < 4; r++) {
        float mx = -3.0e38f;
#pragma unroll
        for (int t = 0; t < 16; t++) mx = fmaxf(mx, acc[t][r]);
#pragma unroll
        for (int off = 1; off < 16; off <<= 1) mx = fmaxf(mx, __shfl_xor(mx, off));
        float sum = 0.f;
#pragma unroll
        for (int t = 0; t < 16; t++) {
            float p = exp2f((acc[t][r] - mx) * se);
            acc[t][r] = p;
            sum += p;
        }
#pragma unroll
        for (int off = 1; off < 16; off <<= 1) sum += __shfl_xor(sum, off);
        const int row = wave * 16 + (lane >> 4) * 4 + r;
#pragma unroll
        for (int t = 0; t < 16; t++)
            smem[PS_OFF + row * 264 + t * 16 + (lane & 15)] = f2bf(acc[t][r]);
        if ((lane & 15) == 0) linv[row] = 1.0f / sum;
    }

    // ---- phase 3: O = P @ Vsel, 2x2 waves over 64x128; stage 2 V chunks/iter
    const int wm2 = wave >> 1, wn2 = wave & 1;
    f32x4 acc2[2][4];
#pragma unroll
    for (int i = 0; i < 2; i++)
#pragma unroll
        for (int j = 0; j < 4; j++) acc2[i][j] = f32x4{0.f, 0.f, 0.f, 0.f};

#pragma unroll
    for (int c2 = 0; c2 < 4; c2++) {           // j-chunks of 64
        // stage Vs chunks (region disjoint from Ps; phase1 drained by barrier above)
#pragma unroll
        for (int c = 0; c < 2; c++) {
            const int j0 = c2 * 64 + c * 32;
#pragma unroll
            for (int q = 0; q < 2; q++)
                load_lds16(Vh + (wave * 32 + q * 16 + lr) * 256 + j0 + scc,
                           &smem[VS_OFF(c) + (wave * 32 + q * 16) * 32]);
        }
        __syncthreads();   // staged V + (first iter) Ps visible
#pragma unroll
        for (int c = 0; c < 2; c++) {
            const int j0 = c2 * 64 + c * 32;
            bf16x8 af2[2], bf2v[4];
#pragma unroll
            for (int s2 = 0; s2 < 2; s2++)
                af2[s2] = *(const bf16x8*)&smem[PS_OFF + (wm2 * 32 + s2 * 16 + (lane & 15)) * 264 + j0 + (lane >> 4) * 8];
#pragma unroll
            for (int t2 = 0; t2 < 4; t2++)
                bf2v[t2] = *(const bf16x8*)&smem[VS_OFF(c) + (wn2 * 64 + t2 * 16 + (lane & 15)) * 32 + rc];
#pragma unroll
            for (int s2 = 0; s2 < 2; s2++)
#pragma unroll
                for (int t2 = 0; t2 < 4; t2++)
                    acc2[s2][t2] = __builtin_amdgcn_mfma_f32_16x16x32_bf16(af2[s2], bf2v[t2], acc2[s2][t2], 0, 0, 0);
        }
        __syncthreads();   // V frag reads done before next stage overwrites
    }

    // ---- epilogue: divide by row sum, write Att[token][h*128+d]
#pragma unroll
    for (int s2 = 0; s2 < 2; s2++) {
#pragma unroll
        for (int t2 = 0; t2 < 4; t2++) {
            const int d = wn2 * 64 + t2 * 16 + (lane & 15);
#pragma unroll
            for (int r = 0; r < 4; r++) {
                const int row = wm2 * 32 + s2 * 16 + (lane >> 4) * 4 + r;
                float v = acc2[s2][t2][r] * linv[row];
                Att[(long)(bm + row) * 2048 + h * 128 + d] = f2bf(v);
            }
        }
    }
}

// ---------------------------------------------------------------------------
// prep: blocks [0,4096): fp32->bf16 transposed weights, 64x64 tiles (4 mats);
//       blocks [4096,4608): colsum partials of hs (ranking stage 1)
// ---------------------------------------------------------------------------
__global__ __launch_bounds__(256) void prep_kernel(Ptr4 srcs, unsigned short* __restrict__ WT4,
                                                   const float* __restrict__ hs,
                                                   double* __restrict__ part) {
    const int b = blockIdx.x;
    const int tid = threadIdx.x;
    if (b < 4096) {
        __shared__ float tile[64][65];
        const int z = b >> 10, xy = b & 1023;
        const float* W = srcs.p[z];
        unsigned short* WT = WT4 + (long)z * 4194304;
        const int bx = (xy & 31) * 64;   // n
        const int by = (xy >> 5) * 64;   // k
        const int x = tid & 63, y = tid >> 6;   // y in 0..3
#pragma unroll
        for (int i = 0; i < 64; i += 4)
            tile[y + i][x] = W[(long)(by + y + i) * 2048 + bx + x];
        __syncthreads();
#pragma unroll
        for (int i = 0; i < 64; i += 4)
            WT[(long)(bx + y + i) * 2048 + by + x] = f2bf(tile[x][y + i]);
    } else {
        const int c = b - 4096;                  // 0..511
        const int col = (c & 7) * 256 + tid;
        const int r0  = (c >> 3) * 32;
        double a = 0.0;
#pragma unroll 4
        for (int r = 0; r < 32; r++) a += (double)hs[(long)(r0 + r) * 2048 + col];
        part[(long)(c >> 3) * 2048 + col] = a;
    }
}

__global__ void fill_kernel(float* p, float v, long n) {
    long i = ((long)blockIdx.x * blockDim.x + threadIdx.x) * 4;
    if (i + 3 < n) { p[i] = v; p[i+1] = v; p[i+2] = v; p[i+3] = v; }
}

// ---------------------------------------------------------------------------
// Ranking path
// ---------------------------------------------------------------------------
__global__ __launch_bounds__(256) void mean_qsum_part(const double* __restrict__ part,
                                                      const float* __restrict__ Wq,
                                                      double* __restrict__ partq) {
    __shared__ float hsb[32];
    const int j  = blockIdx.x * 256 + threadIdx.x;
    const int i0 = blockIdx.y * 32;
    if (threadIdx.x < 32) {
        double s = 0.0;
#pragma unroll 4
        for (int g = 0; g < 64; g++) s += part[(long)g * 2048 + i0 + threadIdx.x];
        hsb[threadIdx.x] = (float)(s * (1.0 / 2048.0));
    }
    __syncthreads();
    double a = 0.0;
#pragma unroll 4
    for (int r = 0; r < 32; r++)
        a += (double)hsb[r] * (double)Wq[(long)(i0 + r) * 2048 + j];
    partq[(long)blockIdx.y * 2048 + j] = a;
}

__global__ void qsum_fin(const double* __restrict__ partq, const float* __restrict__ bq,
                         float* __restrict__ qbar) {
    const int j = blockIdx.x * 64 + threadIdx.x;
    double s = (double)bq[j];
#pragma unroll 4
    for (int g = 0; g < 64; g++) s += partq[(long)g * 2048 + j];
    qbar[j] = (float)s;
}

__global__ __launch_bounds__(256) void u_kernel(const float* __restrict__ Wk,
                                                const float* __restrict__ qbar,
                                                float* __restrict__ U) {
    const int i = blockIdx.x, t = threadIdx.x;
#pragma unroll
    for (int r = 0; r < 2; r++) {
        const int e = r * 1024 + t * 4;
        float4 w = *(const float4*)(Wk + (long)i * 2048 + e);
        float4 q = *(const float4*)(qbar + e);
        float a = w.x * q.x + w.y * q.y + w.z * q.z + w.w * q.w;
#pragma unroll
        for (int off = 16; off; off >>= 1) a += __shfl_xor(a, off);
        if ((t & 31) == 0) U[(long)i * 16 + r * 8 + (t >> 5)] = a;
    }
}

// ---------------------------------------------------------------------------
// fused: HSb = bf16(hs row) AND imp[h,m] = hs[m,:] . U[:,h], 4 rows/block.
// Register-resident, float4-vectorized; accumulation order matches the
// original scalar version -> imp bit-identical -> identical top-k selection.
// ---------------------------------------------------------------------------
__global__ __launch_bounds__(256) void cast_imp_kernel(const float* __restrict__ hs,
                                                       const float* __restrict__ U,
                                                       unsigned short* __restrict__ HSb,
                                                       float* __restrict__ imp) {
    __shared__ float red[4][4][16];            // [wavegroup][row][head]
    const int m0 = blockIdx.x * 4, t = threadIdx.x;

    float va[4][8];
#pragma unroll
    for (int r = 0; r < 4; r++) {
        const float4 v0 = *(const float4*)(hs + (long)(m0 + r) * 2048 + t * 8);
        const float4 v1 = *(const float4*)(hs + (long)(m0 + r) * 2048 + t * 8 + 4);
        va[r][0] = v0.x; va[r][1] = v0.y; va[r][2] = v0.z; va[r][3] = v0.w;
        va[r][4] = v1.x; va[r][5] = v1.y; va[r][6] = v1.z; va[r][7] = v1.w;
        u16x8 hb;
#pragma unroll
        for (int j = 0; j < 8; j++) hb[j] = f2bf(va[r][j]);
        *(u16x8*)(HSb + (long)(m0 + r) * 2048 + t * 8) = hb;
    }

    float p[4][16];
#pragma unroll
    for (int r = 0; r < 4; r++)
#pragma unroll
        for (int h = 0; h < 16; h++) p[r][h] = 0.f;

    const float4* Uq = (const float4*)(U + (long)t * 128);   // rows t*8..t*8+8
#pragma unroll
    for (int j = 0; j < 8; j++) {
        const float4 u0 = Uq[j * 4 + 0];
        const float4 u1 = Uq[j * 4 + 1];
        const float4 u2 = Uq[j * 4 + 2];
        const float4 u3 = Uq[j * 4 + 3];
#pragma unroll
        for (int r = 0; r < 4; r++) {
            const float v = va[r][j];
            p[r][0]  += v * u0.x; p[r][1]  += v * u0.y; p[r][2]  += v * u0.z; p[r][3]  += v * u0.w;
            p[r][4]  += v * u1.x; p[r][5]  += v * u1.y; p[r][6]  += v * u1.z; p[r][7]  += v * u1.w;
            p[r][8]  += v * u2.x; p[r][9]  += v * u2.y; p[r][10] += v * u2.z; p[r][11] += v * u2.w;
            p[r][12] += v * u3.x; p[r][13] += v * u3.y; p[r][14] += v * u3.z; p[r][15] += v * u3.w;
        }
    }

#pragma unroll
    for (int off = 32; off; off >>= 1)
#pragma unroll
        for (int r = 0; r < 4; r++)
#pragma unroll
            for (int h = 0; h < 16; h++) p[r][h] += __shfl_down(p[r][h], off);
    if ((t & 63) == 0)
#pragma unroll
        for (int r = 0; r < 4; r++)
#pragma unroll
            for (int h = 0; h < 16; h++) red[t >> 6][r][h] = p[r][h];
    __syncthreads();
    if (t < 64) {
        const int h = t & 15, r = t >> 4;
        imp[(long)h * 2048 + m0 + r] =
            red[0][r][h] + red[1][r][h] + red[2][r][h] + red[3][r][h];
    }
}

// ---------------------------------------------------------------------------
// exact top-256 per head, emitting FORWARD map idx[h][rank] = token.
// ---------------------------------------------------------------------------
__global__ __launch_bounds__(64) void topk_idx(const float* __restrict__ imp,
                                               int* __restrict__ idx) {
    const int h = blockIdx.x;
    const int lane = threadIdx.x;
    unsigned u[32];
#pragma unroll
    for (int r = 0; r < 32; r++) {
        unsigned x = __float_as_uint(imp[(long)h * 2048 + r * 64 + lane]);
        u[r] = (x & 0x80000000u) ? ~x : (x | 0x80000000u);
    }
    unsigned cur = 0;
    for (int b = 31; b >= 0; b--) {
        const unsigned cand = cur | (1u << b);
        int tot = 0;
#pragma unroll
        for (int r = 0; r < 32; r++)
            tot += (int)__popcll(__ballot(u[r] >= cand));
        if (tot >= 256) cur = cand;
    }
    const unsigned long long below = (1ull << lane) - 1ull;
    int pos[32];
    int base = 0;
#pragma unroll
    for (int r = 0; r < 32; r++) {
        const bool q = u[r] > cur;
        const unsigned long long m = __ballot(q);
        pos[r] = q ? base + (int)__popcll(m & below) : -1;
        base += (int)__popcll(m);
    }
    // ties at threshold continue from the strict count
#pragma unroll
    for (int r = 0; r < 32; r++) {
        const bool q = (u[r] == cur);
        const unsigned long long m = __ballot(q);
        if (q) {
            const int p = base + (int)__popcll(m & below);
            pos[r] = (p < 256) ? p : -1;
        }
        base += (int)__popcll(m);
    }
#pragma unroll
    for (int r = 0; r < 32; r++)
        if (pos[r] >= 0) idx[h * 256 + pos[r]] = r * 64 + lane;
}

// ---------------------------------------------------------------------------
extern "C" void kernel_launch(void* const* d_in, const int* in_sizes, int n_in,
                              void* d_out, int out_size, void* d_ws, size_t ws_size,
                              hipStream_t stream)
{
    const float* hs = (const float*)d_in[0];
    const float* Wq = (const float*)d_in[1];
    const float* bq = (const float*)d_in[2];
    const float* Wk = (const float*)d_in[3];
    const float* bk = (const float*)d_in[4];
    const float* Wv = (const float*)d_in[5];
    const float* bv = (const float*)d_in[6];
    const float* Wo = (const float*)d_in[7];
    const float* bo = (const float*)d_in[8];

    char* ws = (char*)d_ws;
    size_t off = 0;
    auto alloc = [&](size_t b) -> void* {
        void* p = ws + off;
        off = (off + b + 255) & ~(size_t)255;
        return p;
    };
    unsigned short* HSb   = (unsigned short*)alloc(8388608);     // 2048x2048 bf16
    unsigned short* WT4   = (unsigned short*)alloc(4 * 8388608); // WqT|WkT|WvT|WoT
    unsigned short* Qb    = (unsigned short*)alloc(8388608);     // Q [2048][2048]
    unsigned short* Att   = (unsigned short*)alloc(8388608);
    unsigned short* Ksel  = (unsigned short*)alloc(1048576);     // [16][256][128]
    unsigned short* VselT = (unsigned short*)alloc(1048576);     // [16][128][256]
    double* part  = (double*)alloc(1048576);                     // [64][2048]
    double* partq = (double*)alloc(1048576);                     // [64][2048]
    float* qbar  = (float*)alloc(8192);
    float* U     = (float*)alloc(131072);                        // [2048][16]
    float* imp   = (float*)alloc(131072);                        // [16][2048]
    int*   idx   = (int*)alloc(16384);                           // [16][256]

    if (off > ws_size) {
        fill_kernel<<<4096, 256, 0, stream>>>((float*)d_out, 12345.0f, (long)out_size);
        return;
    }

    unsigned short* WoT = WT4 + 3 * 4194304;

    // 1. weight transposes (64x64 tiles) + colsum partials (fused)
    prep_kernel<<<4608, 256, 0, stream>>>(Ptr4{{Wq, Wk, Wv, Wo}}, WT4, hs, part);

    // 2-5. ranking chain (exact, deterministic)
    mean_qsum_part<<<dim3(8, 64), 256, 0, stream>>>(part, Wq, partq);
    qsum_fin<<<32, 64, 0, stream>>>(partq, bq, qbar);
    u_kernel<<<2048, 256, 0, stream>>>(Wk, qbar, U);
    cast_imp_kernel<<<512, 256, 0, stream>>>(hs, U, HSb, imp);

    // 6. top-256 per head -> forward map idx[h][rank] = token
    topk_idx<<<16, 64, 0, stream>>>(imp, idx);

    // 7. combined QKV: 128 gathered-KV blocks (first) + 512 Q blocks (128x64)
    gemm_qkv<<<640, 256, 0, stream>>>(HSb, WT4, bq, bk, bv, idx, Qb, Ksel, VselT);

    // 8. fused attention: S, softmax, PV  (64-query tiles)
    attn_kernel<<<dim3(32, 16), 256, 0, stream>>>(Qb, Ksel, VselT, Att);

    // 9. O GEMM full-K, 128x64 tiles, direct fp32 write with bias
    gemm_o<<<512, 256, 0, stream>>>(Att, WoT, bo, (float*)d_out);
}